// Round 19
// baseline (330.722 us; speedup 1.0000x reference)
//
#include <hip/hip_runtime.h>
#include <hip/hip_bf16.h>
#include <math.h>

#define NN 20000          // nodes
#define NE 320000         // edges (without self loops)
#define ET (NE + NN)      // edges + self loops
#define NG 64             // graphs
#define HEADS 4
#define HID 128
#define OUTC (HEADS * HID)   // 512
#define SLOPE 0.2f

__device__ __forceinline__ float lrelu(float v) { return v > 0.f ? v : SLOPE * v; }

// ---------------- CSR build ----------------
__global__ void k_hist(const int* __restrict__ ei, int* __restrict__ deg) {
  int e = blockIdx.x * blockDim.x + threadIdx.x;
  if (e >= ET) return;
  int dst = (e < NE) ? ei[NE + e] : (e - NE);
  atomicAdd(&deg[dst], 1);
}

__global__ void k_scan(const int* __restrict__ deg, int* __restrict__ row_start,
                       int* __restrict__ cursor) {
  __shared__ int sums[1024];
  int tid = threadIdx.x;
  const int PER = (NN + 1023) / 1024;   // 20
  int base = tid * PER;
  int local = 0;
  for (int i = 0; i < PER; ++i) { int idx = base + i; if (idx < NN) local += deg[idx]; }
  sums[tid] = local;
  __syncthreads();
  for (int off = 1; off < 1024; off <<= 1) {
    int v = (tid >= off) ? sums[tid - off] : 0;
    __syncthreads();
    sums[tid] += v;
    __syncthreads();
  }
  int run = sums[tid] - local;  // exclusive prefix
  for (int i = 0; i < PER; ++i) {
    int idx = base + i;
    if (idx < NN) { row_start[idx] = run; cursor[idx] = run; run += deg[idx]; }
  }
  if (tid == 1023) row_start[NN] = sums[1023];
}

__global__ void k_scatter(const int* __restrict__ ei, int* __restrict__ cursor,
                          int* __restrict__ csr_src) {
  int e = blockIdx.x * blockDim.x + threadIdx.x;
  if (e >= ET) return;
  int src, dst;
  if (e < NE) { src = ei[e]; dst = ei[NE + e]; }
  else        { src = e - NE; dst = src; }
  int pos = atomicAdd(&cursor[dst], 1);
  csr_src[pos] = src;
}

// ---------------- merged watt for all 3 layers ----------------
__global__ void k_watt3(const float* __restrict__ W1, const float* __restrict__ as1,
                        const float* __restrict__ ad1, const float* __restrict__ W2,
                        const float* __restrict__ as2, const float* __restrict__ ad2,
                        const float* __restrict__ W3, const float* __restrict__ as3,
                        const float* __restrict__ ad3, float* __restrict__ watt1,
                        float* __restrict__ watt2, float* __restrict__ watt3) {
  int b = blockIdx.x;   // 0..267
  const float *W, *as, *ad;
  float* wo;
  int k;
  if (b < 12)       { k = b;       W = W1; as = as1; ad = ad1; wo = watt1; }
  else if (b < 140) { k = b - 12;  W = W2; as = as2; ad = ad2; wo = watt2; }
  else              { k = b - 140; W = W3; as = as3; ad = ad3; wo = watt3; }
  int tid = threadIdx.x;          // 256 = 32 c-chunks x 8 t
  int t = tid & 7, h = t & 3;
  int c0 = (tid >> 3) * 4;
  const float* av = (t < 4 ? as : ad) + h * HID;
  const float* wr = W + (size_t)k * OUTC + h * HID;
  float4 wv = *reinterpret_cast<const float4*>(&wr[c0]);
  float4 a4 = *reinterpret_cast<const float4*>(&av[c0]);
  float p = wv.x * a4.x + wv.y * a4.y + wv.z * a4.z + wv.w * a4.w;
  __shared__ float lp[32][8];
  lp[tid >> 3][t] = p;
  __syncthreads();
  if (tid < 8) {
    float s = 0.f;
    for (int cc = 0; cc < 32; ++cc) s += lp[cc][tid];
    wo[k * 8 + tid] = s;
  }
}

// ---------------- attention logits, K=12 (layer 1): thread per node ----------------
__global__ void k_esd1(const float* __restrict__ x, const float* __restrict__ watt,
                       float* __restrict__ es, float* __restrict__ ed) {
  int n = blockIdx.x * blockDim.x + threadIdx.x;
  if (n >= NN) return;
  float xr[12];
#pragma unroll
  for (int k = 0; k < 12; ++k) xr[k] = x[(size_t)n * 12 + k];
#pragma unroll
  for (int t = 0; t < 8; ++t) {
    float acc = 0.f;
#pragma unroll
    for (int k = 0; k < 12; ++k) acc += xr[k] * watt[k * 8 + t];
    if (t < 4) es[n * 4 + t] = acc;
    else       ed[n * 4 + (t - 4)] = acc;
  }
}

// ---------------- attention logits, K=128: THREAD per (node, t) ----------------
__global__ void __launch_bounds__(256) k_esd128(
    const float* __restrict__ x, const float* __restrict__ watt,
    float* __restrict__ es, float* __restrict__ ed) {
  __shared__ float sw[HID * 8];
  int tid = threadIdx.x;
  for (int i = tid; i < HID * 8; i += 256) sw[i] = watt[i];
  __syncthreads();
  int local = tid >> 3;        // 0..31
  int t = tid & 7;
  int n = blockIdx.x * 32 + local;   // NN % 32 == 0
  const float4* xr = reinterpret_cast<const float4*>(&x[(size_t)n * HID]);
  float acc = 0.f;
#pragma unroll 8
  for (int kq = 0; kq < 32; ++kq) {
    float4 xv = xr[kq];
    acc += xv.x * sw[(kq * 4 + 0) * 8 + t] + xv.y * sw[(kq * 4 + 1) * 8 + t]
         + xv.z * sw[(kq * 4 + 2) * 8 + t] + xv.w * sw[(kq * 4 + 3) * 8 + t];
  }
  if (t < 4) es[n * 4 + t] = acc;
  else       ed[n * 4 + (t - 4)] = acc;
}

// ---------------- FUSED softmax + x-aggregation, K=128 (layers 2/3) ----------------
__global__ void __launch_bounds__(256, 4) k_aggf(
    const float* __restrict__ x, const float* __restrict__ es,
    const float* __restrict__ ed, const int* __restrict__ row_start,
    const int* __restrict__ csr_src, float* __restrict__ z) {
  __shared__ float sal[4][256];
  int wid = threadIdx.x >> 6;
  int lane = threadIdx.x & 63;
  int n = blockIdx.x * 4 + wid;          // NN % 4 == 0
  int start = row_start[n];
  int deg = row_start[n + 1] - start;
  const int* sp = csr_src + start;
  float4 edv = *reinterpret_cast<const float4*>(&ed[(size_t)n * 4]);
  int c = lane * 2;
  float2 a0c = make_float2(0.f, 0.f), a1c = make_float2(0.f, 0.f);
  float2 a2c = make_float2(0.f, 0.f), a3c = make_float2(0.f, 0.f);
  float d0 = 0.f, d1 = 0.f, d2 = 0.f, d3 = 0.f;
  for (int cb = 0; cb < deg; cb += 64) {
    int m = min(64, deg - cb);
    {
      int kk = cb + ((lane < m) ? lane : (m - 1));   // clamp (m >= 1 always)
      int s = sp[kk];
      float4 e4 = *reinterpret_cast<const float4*>(&es[(size_t)s * 4]);
      float4 ex;
      ex.x = __expf(lrelu(e4.x + edv.x));
      ex.y = __expf(lrelu(e4.y + edv.y));
      ex.z = __expf(lrelu(e4.z + edv.z));
      ex.w = __expf(lrelu(e4.w + edv.w));
      if (lane < m) {
        *reinterpret_cast<float4*>(&sal[wid][lane * 4]) = ex;
        d0 += ex.x; d1 += ex.y; d2 += ex.z; d3 += ex.w;
      }
    }
    asm volatile("s_waitcnt lgkmcnt(0)" ::: "memory");  // cross-lane LDS RAW fence
    int j = 0;
    for (; j + 4 <= m; j += 4) {
      float4 q0 = *reinterpret_cast<const float4*>(&sal[wid][(j + 0) * 4]);
      float4 q1 = *reinterpret_cast<const float4*>(&sal[wid][(j + 1) * 4]);
      float4 q2 = *reinterpret_cast<const float4*>(&sal[wid][(j + 2) * 4]);
      float4 q3 = *reinterpret_cast<const float4*>(&sal[wid][(j + 3) * 4]);
      int s0 = sp[cb + j + 0], s1 = sp[cb + j + 1];
      int s2 = sp[cb + j + 2], s3 = sp[cb + j + 3];
      float2 x0 = *reinterpret_cast<const float2*>(&x[(size_t)s0 * HID + c]);
      float2 x1 = *reinterpret_cast<const float2*>(&x[(size_t)s1 * HID + c]);
      float2 x2 = *reinterpret_cast<const float2*>(&x[(size_t)s2 * HID + c]);
      float2 x3 = *reinterpret_cast<const float2*>(&x[(size_t)s3 * HID + c]);
      a0c.x += q0.x * x0.x; a0c.y += q0.x * x0.y;
      a1c.x += q0.y * x0.x; a1c.y += q0.y * x0.y;
      a2c.x += q0.z * x0.x; a2c.y += q0.z * x0.y;
      a3c.x += q0.w * x0.x; a3c.y += q0.w * x0.y;
      a0c.x += q1.x * x1.x; a0c.y += q1.x * x1.y;
      a1c.x += q1.y * x1.x; a1c.y += q1.y * x1.y;
      a2c.x += q1.z * x1.x; a2c.y += q1.z * x1.y;
      a3c.x += q1.w * x1.x; a3c.y += q1.w * x1.y;
      a0c.x += q2.x * x2.x; a0c.y += q2.x * x2.y;
      a1c.x += q2.y * x2.x; a1c.y += q2.y * x2.y;
      a2c.x += q2.z * x2.x; a2c.y += q2.z * x2.y;
      a3c.x += q2.w * x2.x; a3c.y += q2.w * x2.y;
      a0c.x += q3.x * x3.x; a0c.y += q3.x * x3.y;
      a1c.x += q3.y * x3.x; a1c.y += q3.y * x3.y;
      a2c.x += q3.z * x3.x; a2c.y += q3.z * x3.y;
      a3c.x += q3.w * x3.x; a3c.y += q3.w * x3.y;
    }
    for (; j < m; ++j) {
      float4 q = *reinterpret_cast<const float4*>(&sal[wid][j * 4]);
      int s = sp[cb + j];
      float2 xv = *reinterpret_cast<const float2*>(&x[(size_t)s * HID + c]);
      a0c.x += q.x * xv.x; a0c.y += q.x * xv.y;
      a1c.x += q.y * xv.x; a1c.y += q.y * xv.y;
      a2c.x += q.z * xv.x; a2c.y += q.z * xv.y;
      a3c.x += q.w * xv.x; a3c.y += q.w * xv.y;
    }
  }
#pragma unroll
  for (int off = 1; off < 64; off <<= 1) {
    d0 += __shfl_xor(d0, off);
    d1 += __shfl_xor(d1, off);
    d2 += __shfl_xor(d2, off);
    d3 += __shfl_xor(d3, off);
  }
  float i0 = 0.25f / d0, i1 = 0.25f / d1, i2 = 0.25f / d2, i3 = 0.25f / d3;
  a0c.x *= i0; a0c.y *= i0;
  a1c.x *= i1; a1c.y *= i1;
  a2c.x *= i2; a2c.y *= i2;
  a3c.x *= i3; a3c.y *= i3;
  float* zr = z + (size_t)n * OUTC;
  *reinterpret_cast<float2*>(&zr[0 * HID + c]) = a0c;
  *reinterpret_cast<float2*>(&zr[1 * HID + c]) = a1c;
  *reinterpret_cast<float2*>(&zr[2 * HID + c]) = a2c;
  *reinterpret_cast<float2*>(&zr[3 * HID + c]) = a3c;
}

// ---------------- FUSED softmax + x-aggregation, K=12 (layer 1) ----------------
__global__ void __launch_bounds__(256, 4) k_aggf1(
    const float* __restrict__ x, const float* __restrict__ es,
    const float* __restrict__ ed, const int* __restrict__ row_start,
    const int* __restrict__ csr_src, float* __restrict__ z1) {
  __shared__ float sal[4][256];
  int wid = threadIdx.x >> 6;
  int lane = threadIdx.x & 63;
  int n = blockIdx.x * 4 + wid;
  int start = row_start[n];
  int deg = row_start[n + 1] - start;
  const int* sp = csr_src + start;
  float4 edv = *reinterpret_cast<const float4*>(&ed[(size_t)n * 4]);
  int h = lane >> 4;
  int cr = lane & 15;
  int cc = cr < 12 ? cr : 11;    // clamp: lanes 12-15 compute garbage, never stored
  float acc = 0.f;
  float d0 = 0.f, d1 = 0.f, d2 = 0.f, d3 = 0.f;
  for (int cb = 0; cb < deg; cb += 64) {
    int m = min(64, deg - cb);
    {
      int kk = cb + ((lane < m) ? lane : (m - 1));
      int s = sp[kk];
      float4 e4 = *reinterpret_cast<const float4*>(&es[(size_t)s * 4]);
      float4 ex;
      ex.x = __expf(lrelu(e4.x + edv.x));
      ex.y = __expf(lrelu(e4.y + edv.y));
      ex.z = __expf(lrelu(e4.z + edv.z));
      ex.w = __expf(lrelu(e4.w + edv.w));
      if (lane < m) {
        *reinterpret_cast<float4*>(&sal[wid][lane * 4]) = ex;
        d0 += ex.x; d1 += ex.y; d2 += ex.z; d3 += ex.w;
      }
    }
    asm volatile("s_waitcnt lgkmcnt(0)" ::: "memory");
    int j = 0;
    for (; j + 4 <= m; j += 4) {
      float ah0 = sal[wid][(j + 0) * 4 + h];
      float ah1 = sal[wid][(j + 1) * 4 + h];
      float ah2 = sal[wid][(j + 2) * 4 + h];
      float ah3 = sal[wid][(j + 3) * 4 + h];
      int s0 = sp[cb + j + 0], s1 = sp[cb + j + 1];
      int s2 = sp[cb + j + 2], s3 = sp[cb + j + 3];
      float x0 = x[(size_t)s0 * 12 + cc];
      float x1 = x[(size_t)s1 * 12 + cc];
      float x2 = x[(size_t)s2 * 12 + cc];
      float x3 = x[(size_t)s3 * 12 + cc];
      acc += ah0 * x0 + ah1 * x1 + ah2 * x2 + ah3 * x3;
    }
    for (; j < m; ++j) {
      float ah = sal[wid][j * 4 + h];
      int s = sp[cb + j];
      acc += ah * x[(size_t)s * 12 + cc];
    }
  }
#pragma unroll
  for (int off = 1; off < 64; off <<= 1) {
    d0 += __shfl_xor(d0, off);
    d1 += __shfl_xor(d1, off);
    d2 += __shfl_xor(d2, off);
    d3 += __shfl_xor(d3, off);
  }
  float dh = (h == 0) ? d0 : (h == 1) ? d1 : (h == 2) ? d2 : d3;
  float ivh = 0.25f / dh;
  if (cr < 12) z1[(size_t)n * 48 + h * 12 + cr] = acc * ivh;
}

// ---------------- full-K GEMM with fused epilogue (layer 1, K=48) ----------------
template <int KTOT, int KH, int BK>
__global__ void k_gemm_full(const float* __restrict__ z, const float* __restrict__ W,
                            const float* __restrict__ bias, float* __restrict__ xout) {
  const int BM = 64, BN = 64;
  __shared__ float sAT[BK][BM + 4];
  __shared__ float sB[BK][BN];
  int tid = threadIdx.x;
  int r0 = blockIdx.y * BM;
  int cb = blockIdx.x * BN;
  int tx = tid & 15, ty = tid >> 4;
  int m0 = ty * 4, n0 = tx * 4;
  float acc[4][4] = {};
  for (int k0 = 0; k0 < KTOT; k0 += BK) {
    const int AF4 = BM * BK / 4;
    for (int idx = tid; idx < AF4; idx += 256) {
      int r = idx / (BK / 4);
      int kq = idx % (BK / 4);
      int row = r0 + r;
      float4 v = make_float4(0.f, 0.f, 0.f, 0.f);
      if (row < NN) v = *reinterpret_cast<const float4*>(&z[(size_t)row * KTOT + k0 + kq * 4]);
      sAT[kq * 4 + 0][r] = v.x;
      sAT[kq * 4 + 1][r] = v.y;
      sAT[kq * 4 + 2][r] = v.z;
      sAT[kq * 4 + 3][r] = v.w;
    }
    const int BF4 = BK * BN / 4;
    for (int idx = tid; idx < BF4; idx += 256) {
      int kr = idx / 16, nq = idx & 15;
      int kk = k0 + kr;
      int h = kk / KH, k = kk % KH;
      float4 v = *reinterpret_cast<const float4*>(&W[(size_t)k * OUTC + h * HID + cb + nq * 4]);
      *reinterpret_cast<float4*>(&sB[kr][nq * 4]) = v;
    }
    __syncthreads();
#pragma unroll 4
    for (int kk = 0; kk < BK; ++kk) {
      float4 a = *reinterpret_cast<const float4*>(&sAT[kk][m0]);
      float4 b = *reinterpret_cast<const float4*>(&sB[kk][n0]);
      acc[0][0] += a.x * b.x; acc[0][1] += a.x * b.y; acc[0][2] += a.x * b.z; acc[0][3] += a.x * b.w;
      acc[1][0] += a.y * b.x; acc[1][1] += a.y * b.y; acc[1][2] += a.y * b.z; acc[1][3] += a.y * b.w;
      acc[2][0] += a.z * b.x; acc[2][1] += a.z * b.y; acc[2][2] += a.z * b.z; acc[2][3] += a.z * b.w;
      acc[3][0] += a.w * b.x; acc[3][1] += a.w * b.y; acc[3][2] += a.w * b.z; acc[3][3] += a.w * b.w;
    }
    __syncthreads();
  }
  float4 bv = *reinterpret_cast<const float4*>(&bias[cb + n0]);
#pragma unroll
  for (int i = 0; i < 4; ++i) {
    int row = r0 + m0 + i;
    if (row < NN) {
      float4 o;
      o.x = fmaxf(acc[i][0] + bv.x, 0.f);
      o.y = fmaxf(acc[i][1] + bv.y, 0.f);
      o.z = fmaxf(acc[i][2] + bv.z, 0.f);
      o.w = fmaxf(acc[i][3] + bv.w, 0.f);
      *reinterpret_cast<float4*>(&xout[(size_t)row * HID + cb + n0]) = o;
    }
  }
}

// ---------------- K-split GEMM: BM=64 x BN=128, NKC chunks ----------------
template <int KTOT, int KH, int BK, int KCH>
__global__ void k_gemm_ks(const float* __restrict__ z, const float* __restrict__ W,
                          float* __restrict__ part) {
  const int BM = 64, BN = 128;
  __shared__ float sAT[BK][BM + 4];
  __shared__ float sB[BK][BN];
  int tid = threadIdx.x;
  int r0 = blockIdx.y * BM;
  int kc = blockIdx.z;
  int tx = tid & 15, ty = tid >> 4;
  int m0 = ty * 4, n0 = tx * 4;
  float acc0[4][4] = {};
  float acc1[4][4] = {};
  for (int k0 = kc * KCH; k0 < (kc + 1) * KCH; k0 += BK) {
    const int AF4 = BM * BK / 4;
    for (int idx = tid; idx < AF4; idx += 256) {
      int r = idx / (BK / 4);
      int kq = idx % (BK / 4);
      int row = r0 + r;
      float4 v = make_float4(0.f, 0.f, 0.f, 0.f);
      if (row < NN) v = *reinterpret_cast<const float4*>(&z[(size_t)row * KTOT + k0 + kq * 4]);
      sAT[kq * 4 + 0][r] = v.x;
      sAT[kq * 4 + 1][r] = v.y;
      sAT[kq * 4 + 2][r] = v.z;
      sAT[kq * 4 + 3][r] = v.w;
    }
    const int BF4 = BK * BN / 4;          // 1024
    for (int idx = tid; idx < BF4; idx += 256) {
      int kr = idx >> 5, nq = idx & 31;
      int kk = k0 + kr;
      int h = kk / KH, k = kk % KH;
      float4 v = *reinterpret_cast<const float4*>(&W[(size_t)k * OUTC + h * HID + nq * 4]);
      *reinterpret_cast<float4*>(&sB[kr][nq * 4]) = v;
    }
    __syncthreads();
#pragma unroll 4
    for (int kk = 0; kk < BK; ++kk) {
      float4 a = *reinterpret_cast<const float4*>(&sAT[kk][m0]);
      float4 b0 = *reinterpret_cast<const float4*>(&sB[kk][n0]);
      float4 b1 = *reinterpret_cast<const float4*>(&sB[kk][64 + n0]);
      acc0[0][0] += a.x * b0.x; acc0[0][1] += a.x * b0.y; acc0[0][2] += a.x * b0.z; acc0[0][3] += a.x * b0.w;
      acc0[1][0] += a.y * b0.x; acc0[1][1] += a.y * b0.y; acc0[1][2] += a.y * b0.z; acc0[1][3] += a.y * b0.w;
      acc0[2][0] += a.z * b0.x; acc0[2][1] += a.z * b0.y; acc0[2][2] += a.z * b0.z; acc0[2][3] += a.z * b0.w;
      acc0[3][0] += a.w * b0.x; acc0[3][1] += a.w * b0.y; acc0[3][2] += a.w * b0.z; acc0[3][3] += a.w * b0.w;
      acc1[0][0] += a.x * b1.x; acc1[0][1] += a.x * b1.y; acc1[0][2] += a.x * b1.z; acc1[0][3] += a.x * b1.w;
      acc1[1][0] += a.y * b1.x; acc1[1][1] += a.y * b1.y; acc1[1][2] += a.y * b1.z; acc1[1][3] += a.y * b1.w;
      acc1[2][0] += a.z * b1.x; acc1[2][1] += a.z * b1.y; acc1[2][2] += a.z * b1.z; acc1[2][3] += a.z * b1.w;
      acc1[3][0] += a.w * b1.x; acc1[3][1] += a.w * b1.y; acc1[3][2] += a.w * b1.z; acc1[3][3] += a.w * b1.w;
    }
    __syncthreads();
  }
#pragma unroll
  for (int i = 0; i < 4; ++i) {
    int row = r0 + m0 + i;
    if (row < NN) {
      float4 v0 = make_float4(acc0[i][0], acc0[i][1], acc0[i][2], acc0[i][3]);
      float4 v1 = make_float4(acc1[i][0], acc1[i][1], acc1[i][2], acc1[i][3]);
      float* pr = &part[((size_t)kc * NN + row) * HID];
      *reinterpret_cast<float4*>(&pr[n0]) = v0;
      *reinterpret_cast<float4*>(&pr[64 + n0]) = v1;
    }
  }
}

// ---------------- epilogue: sum NKC partials + bias + relu (+pool) ----------------
template <int POOL, int NKC>
__global__ void k_epi(const float* __restrict__ part, const float* __restrict__ bias,
                      const int* __restrict__ batch, float* __restrict__ xout,
                      float* __restrict__ gsums) {
  int tid = threadIdx.x;
  int row = blockIdx.x * 2 + (tid >> 7);
  int c = tid & 127;
  float o = bias[c];
#pragma unroll
  for (int kc = 0; kc < NKC; ++kc)
    o += part[((size_t)kc * NN + row) * HID + c];
  o = fmaxf(o, 0.f);
  if (POOL) {
    atomicAdd(&gsums[(size_t)batch[row] * HID + c], o);
  } else {
    xout[(size_t)row * HID + c] = o;
  }
}

// ---------------- epilogue FUSED with next layer's logits ----------------
// Sums NKC partials + bias + relu -> xout, then computes es/ed for the NEXT layer
// from the row staged in LDS (8 dot products of length 128 per row).
template <int NKC>
__global__ void k_epi_esd(const float* __restrict__ part, const float* __restrict__ bias,
                          float* __restrict__ xout, const float* __restrict__ watt,
                          float* __restrict__ es, float* __restrict__ ed) {
  __shared__ float sx[2][HID];
  int tid = threadIdx.x;
  int slot = tid >> 7;
  int row = blockIdx.x * 2 + slot;
  int c = tid & 127;
  float o = bias[c];
#pragma unroll
  for (int kc = 0; kc < NKC; ++kc)
    o += part[((size_t)kc * NN + row) * HID + c];
  o = fmaxf(o, 0.f);
  xout[(size_t)row * HID + c] = o;
  sx[slot][c] = o;
  __syncthreads();
  int t = tid & 127;
  if (t < 8) {
    int r = blockIdx.x * 2 + slot;
    float acc = 0.f;
#pragma unroll 16
    for (int k = 0; k < HID; ++k) acc += sx[slot][k] * watt[k * 8 + t];
    if (t < 4) es[r * 4 + t] = acc;
    else       ed[r * 4 + (t - 4)] = acc;
  }
}

// ---------------- MLP head ----------------
__global__ void k_mlp(const float* __restrict__ sums, const int* __restrict__ batch,
                      const float* __restrict__ bst, const float* __restrict__ M1,
                      const float* __restrict__ mb1, const float* __restrict__ M2,
                      const float* __restrict__ mb2, const float* __restrict__ M3,
                      const float* __restrict__ mb3, float* __restrict__ out) {
  int g = blockIdx.x, tid = threadIdx.x;  // 128 threads
  int lo = 0, hi = NN;
  while (lo < hi) { int mid = (lo + hi) >> 1; if (batch[mid] < g) lo = mid + 1; else hi = mid; }
  int s = lo;
  lo = s; hi = NN;
  while (lo < hi) { int mid = (lo + hi) >> 1; if (batch[mid] < g + 1) lo = mid + 1; else hi = mid; }
  int e = lo;
  float cnt = (float)(e - s);
  float pooled = sums[g * HID + tid] / fmaxf(cnt, 1.f);
  __shared__ float z[HID + 1];
  __shared__ float z1[HID];
  __shared__ float z2[64];
  z[tid] = pooled;
  if (tid == 0) z[HID] = log1pf(bst[g]);
  __syncthreads();
  float a1 = mb1[tid];
  for (int k = 0; k < HID + 1; ++k) a1 += z[k] * M1[k * HID + tid];
  z1[tid] = a1 > 0.f ? a1 : 0.f;
  __syncthreads();
  if (tid < 64) {
    float a2 = mb2[tid];
    for (int k = 0; k < HID; ++k) a2 += z1[k] * M2[k * 64 + tid];
    z2[tid] = a2 > 0.f ? a2 : 0.f;
  }
  __syncthreads();
  if (tid < 2) {
    float a3 = mb3[tid];
    for (int k = 0; k < 64; ++k) a3 += z2[k] * M3[k * 2 + tid];
    out[g * 2 + tid] = a3;
  }
}

extern "C" void kernel_launch(void* const* d_in, const int* in_sizes, int n_in,
                              void* d_out, int out_size, void* d_ws, size_t ws_size,
                              hipStream_t stream) {
  const float* x   = (const float*)d_in[0];
  const int*   ei  = (const int*)d_in[1];
  const int*   bat = (const int*)d_in[2];
  const float* bst = (const float*)d_in[3];
  const float* W1 = (const float*)d_in[4];
  const float* as1 = (const float*)d_in[5];
  const float* ad1 = (const float*)d_in[6];
  const float* b1 = (const float*)d_in[7];
  const float* W2 = (const float*)d_in[8];
  const float* as2 = (const float*)d_in[9];
  const float* ad2 = (const float*)d_in[10];
  const float* b2 = (const float*)d_in[11];
  const float* W3 = (const float*)d_in[12];
  const float* as3 = (const float*)d_in[13];
  const float* ad3 = (const float*)d_in[14];
  const float* b3 = (const float*)d_in[15];
  const float* M1 = (const float*)d_in[16];
  const float* mb1 = (const float*)d_in[17];
  const float* M2 = (const float*)d_in[18];
  const float* mb2 = (const float*)d_in[19];
  const float* M3 = (const float*)d_in[20];
  const float* mb3 = (const float*)d_in[21];
  float* out = (float*)d_out;

  // x8 K-split needs part = 8*NN*128*4 = 81.92MB (total ws ~150MB); x4 = 41MB.
  const bool use8 = ws_size >= (size_t)170 * 1024 * 1024;
  const bool use4 = !use8 && ws_size >= (size_t)110 * 1024 * 1024;
  const int nkc = use8 ? 8 : (use4 ? 4 : 2);

  char* ws = (char*)d_ws;
  auto alloc = [&](size_t bytes) -> void* {
    void* p = (void*)ws;
    ws += (bytes + 255) & ~(size_t)255;
    return p;
  };
  float* z_buf  = (float*)alloc((size_t)NN * OUTC * 4);   // aggregated x (41MB)
  float* z1_buf = (float*)alloc((size_t)NN * 48 * 4);
  float* x_buf  = (float*)alloc((size_t)NN * HID * 4);
  float* e_src  = (float*)alloc((size_t)NN * 4 * 4);
  float* e_dst  = (float*)alloc((size_t)NN * 4 * 4);
  int*   deg    = (int*)alloc((size_t)NN * 4);
  int*   rowst  = (int*)alloc((size_t)(NN + 1) * 4);
  int*   cursor = (int*)alloc((size_t)NN * 4);
  int*   csr    = (int*)alloc((size_t)ET * 4);
  float* part   = (float*)alloc((size_t)nkc * NN * HID * 4);
  float* watt1  = (float*)alloc((size_t)12 * 8 * 4);
  float* watt2  = (float*)alloc((size_t)HID * 8 * 4);
  float* watt3  = (float*)alloc((size_t)HID * 8 * 4);
  float* gsums  = (float*)alloc((size_t)NG * HID * 4);

  // CSR by destination
  hipMemsetAsync(deg, 0, (size_t)NN * 4, stream);
  hipMemsetAsync(gsums, 0, (size_t)NG * HID * 4, stream);
  k_hist<<<(ET + 255) / 256, 256, 0, stream>>>(ei, deg);
  k_scan<<<1, 1024, 0, stream>>>(deg, rowst, cursor);
  k_scatter<<<(ET + 255) / 256, 256, 0, stream>>>(ei, cursor, csr);
  k_watt3<<<268, 256, 0, stream>>>(W1, as1, ad1, W2, as2, ad2, W3, as3, ad3,
                                   watt1, watt2, watt3);

  dim3 pgrid(NN / 4);
  dim3 g1grid(2, (NN + 63) / 64);
  dim3 ks8grid(1, (NN + 63) / 64, 8);
  dim3 ks4grid(1, (NN + 63) / 64, 4);
  dim3 ks2grid(1, (NN + 63) / 64, 2);
  dim3 epigrid(NN / 2);
  // ---- layer 1 (K=12) ----
  k_esd1<<<(NN + 255) / 256, 256, 0, stream>>>(x, watt1, e_src, e_dst);
  k_aggf1<<<pgrid, 256, 0, stream>>>(x, e_src, e_dst, rowst, csr, z1_buf);
  k_gemm_full<48, 12, 48><<<g1grid, 256, 0, stream>>>(z1_buf, W1, b1, x_buf);
  // ---- layer 2 (K=128) ----
  k_esd128<<<NN / 32, 256, 0, stream>>>(x_buf, watt2, e_src, e_dst);
  k_aggf<<<pgrid, 256, 0, stream>>>(x_buf, e_src, e_dst, rowst, csr, z_buf);
  if (use8) {
    k_gemm_ks<512, 128, 32, 64><<<ks8grid, 256, 0, stream>>>(z_buf, W2, part);
    k_epi_esd<8><<<epigrid, 256, 0, stream>>>(part, b2, x_buf, watt3, e_src, e_dst);
  } else if (use4) {
    k_gemm_ks<512, 128, 32, 128><<<ks4grid, 256, 0, stream>>>(z_buf, W2, part);
    k_epi_esd<4><<<epigrid, 256, 0, stream>>>(part, b2, x_buf, watt3, e_src, e_dst);
  } else {
    k_gemm_ks<512, 128, 32, 256><<<ks2grid, 256, 0, stream>>>(z_buf, W2, part);
    k_epi_esd<2><<<epigrid, 256, 0, stream>>>(part, b2, x_buf, watt3, e_src, e_dst);
  }
  // ---- layer 3 (K=128, fused pool; es/ed already computed by k_epi_esd) ----
  k_aggf<<<pgrid, 256, 0, stream>>>(x_buf, e_src, e_dst, rowst, csr, z_buf);
  if (use8) {
    k_gemm_ks<512, 128, 32, 64><<<ks8grid, 256, 0, stream>>>(z_buf, W3, part);
    k_epi<1, 8><<<epigrid, 256, 0, stream>>>(part, b3, bat, x_buf, gsums);
  } else if (use4) {
    k_gemm_ks<512, 128, 32, 128><<<ks4grid, 256, 0, stream>>>(z_buf, W3, part);
    k_epi<1, 4><<<epigrid, 256, 0, stream>>>(part, b3, bat, x_buf, gsums);
  } else {
    k_gemm_ks<512, 128, 32, 256><<<ks2grid, 256, 0, stream>>>(z_buf, W3, part);
    k_epi<1, 2><<<epigrid, 256, 0, stream>>>(part, b3, bat, x_buf, gsums);
  }
  // ---- MLP head ----
  k_mlp<<<NG, 128, 0, stream>>>(gsums, bat, bst, M1, mb1, M2, mb2, M3, mb3, out);
}

// Round 20
// 329.364 us; speedup vs baseline: 1.0041x; 1.0041x over previous
//
#include <hip/hip_runtime.h>
#include <hip/hip_bf16.h>
#include <math.h>

#define NN 20000          // nodes
#define NE 320000         // edges (without self loops)
#define ET (NE + NN)      // edges + self loops
#define NG 64             // graphs
#define HEADS 4
#define HID 128
#define OUTC (HEADS * HID)   // 512
#define SLOPE 0.2f

__device__ __forceinline__ float lrelu(float v) { return v > 0.f ? v : SLOPE * v; }

// ---------------- CSR build ----------------
__global__ void k_hist(const int* __restrict__ ei, int* __restrict__ deg) {
  int e = blockIdx.x * blockDim.x + threadIdx.x;
  if (e >= ET) return;
  int dst = (e < NE) ? ei[NE + e] : (e - NE);
  atomicAdd(&deg[dst], 1);
}

__global__ void k_scan(const int* __restrict__ deg, int* __restrict__ row_start,
                       int* __restrict__ cursor) {
  __shared__ int sums[1024];
  int tid = threadIdx.x;
  const int PER = (NN + 1023) / 1024;   // 20
  int base = tid * PER;
  int local = 0;
  for (int i = 0; i < PER; ++i) { int idx = base + i; if (idx < NN) local += deg[idx]; }
  sums[tid] = local;
  __syncthreads();
  for (int off = 1; off < 1024; off <<= 1) {
    int v = (tid >= off) ? sums[tid - off] : 0;
    __syncthreads();
    sums[tid] += v;
    __syncthreads();
  }
  int run = sums[tid] - local;  // exclusive prefix
  for (int i = 0; i < PER; ++i) {
    int idx = base + i;
    if (idx < NN) { row_start[idx] = run; cursor[idx] = run; run += deg[idx]; }
  }
  if (tid == 1023) row_start[NN] = sums[1023];
}

__global__ void k_scatter(const int* __restrict__ ei, int* __restrict__ cursor,
                          int* __restrict__ csr_src) {
  int e = blockIdx.x * blockDim.x + threadIdx.x;
  if (e >= ET) return;
  int src, dst;
  if (e < NE) { src = ei[e]; dst = ei[NE + e]; }
  else        { src = e - NE; dst = src; }
  int pos = atomicAdd(&cursor[dst], 1);
  csr_src[pos] = src;
}

// ---------------- merged watt for all 3 layers ----------------
__global__ void k_watt3(const float* __restrict__ W1, const float* __restrict__ as1,
                        const float* __restrict__ ad1, const float* __restrict__ W2,
                        const float* __restrict__ as2, const float* __restrict__ ad2,
                        const float* __restrict__ W3, const float* __restrict__ as3,
                        const float* __restrict__ ad3, float* __restrict__ watt1,
                        float* __restrict__ watt2, float* __restrict__ watt3) {
  int b = blockIdx.x;   // 0..267
  const float *W, *as, *ad;
  float* wo;
  int k;
  if (b < 12)       { k = b;       W = W1; as = as1; ad = ad1; wo = watt1; }
  else if (b < 140) { k = b - 12;  W = W2; as = as2; ad = ad2; wo = watt2; }
  else              { k = b - 140; W = W3; as = as3; ad = ad3; wo = watt3; }
  int tid = threadIdx.x;          // 256 = 32 c-chunks x 8 t
  int t = tid & 7, h = t & 3;
  int c0 = (tid >> 3) * 4;
  const float* av = (t < 4 ? as : ad) + h * HID;
  const float* wr = W + (size_t)k * OUTC + h * HID;
  float4 wv = *reinterpret_cast<const float4*>(&wr[c0]);
  float4 a4 = *reinterpret_cast<const float4*>(&av[c0]);
  float p = wv.x * a4.x + wv.y * a4.y + wv.z * a4.z + wv.w * a4.w;
  __shared__ float lp[32][8];
  lp[tid >> 3][t] = p;
  __syncthreads();
  if (tid < 8) {
    float s = 0.f;
    for (int cc = 0; cc < 32; ++cc) s += lp[cc][tid];
    wo[k * 8 + tid] = s;
  }
}

// ---------------- attention logits, K=12 (layer 1): thread per node ----------------
__global__ void k_esd1(const float* __restrict__ x, const float* __restrict__ watt,
                       float* __restrict__ es, float* __restrict__ ed) {
  int n = blockIdx.x * blockDim.x + threadIdx.x;
  if (n >= NN) return;
  float xr[12];
#pragma unroll
  for (int k = 0; k < 12; ++k) xr[k] = x[(size_t)n * 12 + k];
#pragma unroll
  for (int t = 0; t < 8; ++t) {
    float acc = 0.f;
#pragma unroll
    for (int k = 0; k < 12; ++k) acc += xr[k] * watt[k * 8 + t];
    if (t < 4) es[n * 4 + t] = acc;
    else       ed[n * 4 + (t - 4)] = acc;
  }
}

// ---------------- attention logits, K=128: THREAD per (node, t) ----------------
__global__ void __launch_bounds__(256) k_esd128(
    const float* __restrict__ x, const float* __restrict__ watt,
    float* __restrict__ es, float* __restrict__ ed) {
  __shared__ float sw[HID * 8];
  int tid = threadIdx.x;
  for (int i = tid; i < HID * 8; i += 256) sw[i] = watt[i];
  __syncthreads();
  int local = tid >> 3;        // 0..31
  int t = tid & 7;
  int n = blockIdx.x * 32 + local;   // NN % 32 == 0
  const float4* xr = reinterpret_cast<const float4*>(&x[(size_t)n * HID]);
  float acc = 0.f;
#pragma unroll 8
  for (int kq = 0; kq < 32; ++kq) {
    float4 xv = xr[kq];
    acc += xv.x * sw[(kq * 4 + 0) * 8 + t] + xv.y * sw[(kq * 4 + 1) * 8 + t]
         + xv.z * sw[(kq * 4 + 2) * 8 + t] + xv.w * sw[(kq * 4 + 3) * 8 + t];
  }
  if (t < 4) es[n * 4 + t] = acc;
  else       ed[n * 4 + (t - 4)] = acc;
}

// ---------------- FUSED softmax + x-aggregation, K=128 (layers 2/3) ----------------
__global__ void __launch_bounds__(256, 4) k_aggf(
    const float* __restrict__ x, const float* __restrict__ es,
    const float* __restrict__ ed, const int* __restrict__ row_start,
    const int* __restrict__ csr_src, float* __restrict__ z) {
  __shared__ float sal[4][256];
  int wid = threadIdx.x >> 6;
  int lane = threadIdx.x & 63;
  int n = blockIdx.x * 4 + wid;          // NN % 4 == 0
  int start = row_start[n];
  int deg = row_start[n + 1] - start;
  const int* sp = csr_src + start;
  float4 edv = *reinterpret_cast<const float4*>(&ed[(size_t)n * 4]);
  int c = lane * 2;
  float2 a0c = make_float2(0.f, 0.f), a1c = make_float2(0.f, 0.f);
  float2 a2c = make_float2(0.f, 0.f), a3c = make_float2(0.f, 0.f);
  float d0 = 0.f, d1 = 0.f, d2 = 0.f, d3 = 0.f;
  for (int cb = 0; cb < deg; cb += 64) {
    int m = min(64, deg - cb);
    {
      int kk = cb + ((lane < m) ? lane : (m - 1));   // clamp (m >= 1 always)
      int s = sp[kk];
      float4 e4 = *reinterpret_cast<const float4*>(&es[(size_t)s * 4]);
      float4 ex;
      ex.x = __expf(lrelu(e4.x + edv.x));
      ex.y = __expf(lrelu(e4.y + edv.y));
      ex.z = __expf(lrelu(e4.z + edv.z));
      ex.w = __expf(lrelu(e4.w + edv.w));
      if (lane < m) {
        *reinterpret_cast<float4*>(&sal[wid][lane * 4]) = ex;
        d0 += ex.x; d1 += ex.y; d2 += ex.z; d3 += ex.w;
      }
    }
    asm volatile("s_waitcnt lgkmcnt(0)" ::: "memory");  // cross-lane LDS RAW fence
    int j = 0;
    for (; j + 4 <= m; j += 4) {
      float4 q0 = *reinterpret_cast<const float4*>(&sal[wid][(j + 0) * 4]);
      float4 q1 = *reinterpret_cast<const float4*>(&sal[wid][(j + 1) * 4]);
      float4 q2 = *reinterpret_cast<const float4*>(&sal[wid][(j + 2) * 4]);
      float4 q3 = *reinterpret_cast<const float4*>(&sal[wid][(j + 3) * 4]);
      int s0 = sp[cb + j + 0], s1 = sp[cb + j + 1];
      int s2 = sp[cb + j + 2], s3 = sp[cb + j + 3];
      float2 x0 = *reinterpret_cast<const float2*>(&x[(size_t)s0 * HID + c]);
      float2 x1 = *reinterpret_cast<const float2*>(&x[(size_t)s1 * HID + c]);
      float2 x2 = *reinterpret_cast<const float2*>(&x[(size_t)s2 * HID + c]);
      float2 x3 = *reinterpret_cast<const float2*>(&x[(size_t)s3 * HID + c]);
      a0c.x += q0.x * x0.x; a0c.y += q0.x * x0.y;
      a1c.x += q0.y * x0.x; a1c.y += q0.y * x0.y;
      a2c.x += q0.z * x0.x; a2c.y += q0.z * x0.y;
      a3c.x += q0.w * x0.x; a3c.y += q0.w * x0.y;
      a0c.x += q1.x * x1.x; a0c.y += q1.x * x1.y;
      a1c.x += q1.y * x1.x; a1c.y += q1.y * x1.y;
      a2c.x += q1.z * x1.x; a2c.y += q1.z * x1.y;
      a3c.x += q1.w * x1.x; a3c.y += q1.w * x1.y;
      a0c.x += q2.x * x2.x; a0c.y += q2.x * x2.y;
      a1c.x += q2.y * x2.x; a1c.y += q2.y * x2.y;
      a2c.x += q2.z * x2.x; a2c.y += q2.z * x2.y;
      a3c.x += q2.w * x2.x; a3c.y += q2.w * x2.y;
      a0c.x += q3.x * x3.x; a0c.y += q3.x * x3.y;
      a1c.x += q3.y * x3.x; a1c.y += q3.y * x3.y;
      a2c.x += q3.z * x3.x; a2c.y += q3.z * x3.y;
      a3c.x += q3.w * x3.x; a3c.y += q3.w * x3.y;
    }
    for (; j < m; ++j) {
      float4 q = *reinterpret_cast<const float4*>(&sal[wid][j * 4]);
      int s = sp[cb + j];
      float2 xv = *reinterpret_cast<const float2*>(&x[(size_t)s * HID + c]);
      a0c.x += q.x * xv.x; a0c.y += q.x * xv.y;
      a1c.x += q.y * xv.x; a1c.y += q.y * xv.y;
      a2c.x += q.z * xv.x; a2c.y += q.z * xv.y;
      a3c.x += q.w * xv.x; a3c.y += q.w * xv.y;
    }
  }
#pragma unroll
  for (int off = 1; off < 64; off <<= 1) {
    d0 += __shfl_xor(d0, off);
    d1 += __shfl_xor(d1, off);
    d2 += __shfl_xor(d2, off);
    d3 += __shfl_xor(d3, off);
  }
  float i0 = 0.25f / d0, i1 = 0.25f / d1, i2 = 0.25f / d2, i3 = 0.25f / d3;
  a0c.x *= i0; a0c.y *= i0;
  a1c.x *= i1; a1c.y *= i1;
  a2c.x *= i2; a2c.y *= i2;
  a3c.x *= i3; a3c.y *= i3;
  float* zr = z + (size_t)n * OUTC;
  *reinterpret_cast<float2*>(&zr[0 * HID + c]) = a0c;
  *reinterpret_cast<float2*>(&zr[1 * HID + c]) = a1c;
  *reinterpret_cast<float2*>(&zr[2 * HID + c]) = a2c;
  *reinterpret_cast<float2*>(&zr[3 * HID + c]) = a3c;
}

// ---------------- FUSED softmax + x-aggregation, K=12 (layer 1) ----------------
__global__ void __launch_bounds__(256, 4) k_aggf1(
    const float* __restrict__ x, const float* __restrict__ es,
    const float* __restrict__ ed, const int* __restrict__ row_start,
    const int* __restrict__ csr_src, float* __restrict__ z1) {
  __shared__ float sal[4][256];
  int wid = threadIdx.x >> 6;
  int lane = threadIdx.x & 63;
  int n = blockIdx.x * 4 + wid;
  int start = row_start[n];
  int deg = row_start[n + 1] - start;
  const int* sp = csr_src + start;
  float4 edv = *reinterpret_cast<const float4*>(&ed[(size_t)n * 4]);
  int h = lane >> 4;
  int cr = lane & 15;
  int cc = cr < 12 ? cr : 11;    // clamp: lanes 12-15 compute garbage, never stored
  float acc = 0.f;
  float d0 = 0.f, d1 = 0.f, d2 = 0.f, d3 = 0.f;
  for (int cb = 0; cb < deg; cb += 64) {
    int m = min(64, deg - cb);
    {
      int kk = cb + ((lane < m) ? lane : (m - 1));
      int s = sp[kk];
      float4 e4 = *reinterpret_cast<const float4*>(&es[(size_t)s * 4]);
      float4 ex;
      ex.x = __expf(lrelu(e4.x + edv.x));
      ex.y = __expf(lrelu(e4.y + edv.y));
      ex.z = __expf(lrelu(e4.z + edv.z));
      ex.w = __expf(lrelu(e4.w + edv.w));
      if (lane < m) {
        *reinterpret_cast<float4*>(&sal[wid][lane * 4]) = ex;
        d0 += ex.x; d1 += ex.y; d2 += ex.z; d3 += ex.w;
      }
    }
    asm volatile("s_waitcnt lgkmcnt(0)" ::: "memory");
    int j = 0;
    for (; j + 4 <= m; j += 4) {
      float ah0 = sal[wid][(j + 0) * 4 + h];
      float ah1 = sal[wid][(j + 1) * 4 + h];
      float ah2 = sal[wid][(j + 2) * 4 + h];
      float ah3 = sal[wid][(j + 3) * 4 + h];
      int s0 = sp[cb + j + 0], s1 = sp[cb + j + 1];
      int s2 = sp[cb + j + 2], s3 = sp[cb + j + 3];
      float x0 = x[(size_t)s0 * 12 + cc];
      float x1 = x[(size_t)s1 * 12 + cc];
      float x2 = x[(size_t)s2 * 12 + cc];
      float x3 = x[(size_t)s3 * 12 + cc];
      acc += ah0 * x0 + ah1 * x1 + ah2 * x2 + ah3 * x3;
    }
    for (; j < m; ++j) {
      float ah = sal[wid][j * 4 + h];
      int s = sp[cb + j];
      acc += ah * x[(size_t)s * 12 + cc];
    }
  }
#pragma unroll
  for (int off = 1; off < 64; off <<= 1) {
    d0 += __shfl_xor(d0, off);
    d1 += __shfl_xor(d1, off);
    d2 += __shfl_xor(d2, off);
    d3 += __shfl_xor(d3, off);
  }
  float dh = (h == 0) ? d0 : (h == 1) ? d1 : (h == 2) ? d2 : d3;
  float ivh = 0.25f / dh;
  if (cr < 12) z1[(size_t)n * 48 + h * 12 + cr] = acc * ivh;
}

// ---------------- full-K GEMM with fused epilogue (layer 1, K=48) ----------------
template <int KTOT, int KH, int BK>
__global__ void k_gemm_full(const float* __restrict__ z, const float* __restrict__ W,
                            const float* __restrict__ bias, float* __restrict__ xout) {
  const int BM = 64, BN = 64;
  __shared__ float sAT[BK][BM + 4];
  __shared__ float sB[BK][BN];
  int tid = threadIdx.x;
  int r0 = blockIdx.y * BM;
  int cb = blockIdx.x * BN;
  int tx = tid & 15, ty = tid >> 4;
  int m0 = ty * 4, n0 = tx * 4;
  float acc[4][4] = {};
  for (int k0 = 0; k0 < KTOT; k0 += BK) {
    const int AF4 = BM * BK / 4;
    for (int idx = tid; idx < AF4; idx += 256) {
      int r = idx / (BK / 4);
      int kq = idx % (BK / 4);
      int row = r0 + r;
      float4 v = make_float4(0.f, 0.f, 0.f, 0.f);
      if (row < NN) v = *reinterpret_cast<const float4*>(&z[(size_t)row * KTOT + k0 + kq * 4]);
      sAT[kq * 4 + 0][r] = v.x;
      sAT[kq * 4 + 1][r] = v.y;
      sAT[kq * 4 + 2][r] = v.z;
      sAT[kq * 4 + 3][r] = v.w;
    }
    const int BF4 = BK * BN / 4;
    for (int idx = tid; idx < BF4; idx += 256) {
      int kr = idx / 16, nq = idx & 15;
      int kk = k0 + kr;
      int h = kk / KH, k = kk % KH;
      float4 v = *reinterpret_cast<const float4*>(&W[(size_t)k * OUTC + h * HID + cb + nq * 4]);
      *reinterpret_cast<float4*>(&sB[kr][nq * 4]) = v;
    }
    __syncthreads();
#pragma unroll 4
    for (int kk = 0; kk < BK; ++kk) {
      float4 a = *reinterpret_cast<const float4*>(&sAT[kk][m0]);
      float4 b = *reinterpret_cast<const float4*>(&sB[kk][n0]);
      acc[0][0] += a.x * b.x; acc[0][1] += a.x * b.y; acc[0][2] += a.x * b.z; acc[0][3] += a.x * b.w;
      acc[1][0] += a.y * b.x; acc[1][1] += a.y * b.y; acc[1][2] += a.y * b.z; acc[1][3] += a.y * b.w;
      acc[2][0] += a.z * b.x; acc[2][1] += a.z * b.y; acc[2][2] += a.z * b.z; acc[2][3] += a.z * b.w;
      acc[3][0] += a.w * b.x; acc[3][1] += a.w * b.y; acc[3][2] += a.w * b.z; acc[3][3] += a.w * b.w;
    }
    __syncthreads();
  }
  float4 bv = *reinterpret_cast<const float4*>(&bias[cb + n0]);
#pragma unroll
  for (int i = 0; i < 4; ++i) {
    int row = r0 + m0 + i;
    if (row < NN) {
      float4 o;
      o.x = fmaxf(acc[i][0] + bv.x, 0.f);
      o.y = fmaxf(acc[i][1] + bv.y, 0.f);
      o.z = fmaxf(acc[i][2] + bv.z, 0.f);
      o.w = fmaxf(acc[i][3] + bv.w, 0.f);
      *reinterpret_cast<float4*>(&xout[(size_t)row * HID + cb + n0]) = o;
    }
  }
}

// ---------------- K-split GEMM: BM=64 x BN=128, NKC chunks ----------------
template <int KTOT, int KH, int BK, int KCH>
__global__ void k_gemm_ks(const float* __restrict__ z, const float* __restrict__ W,
                          float* __restrict__ part) {
  const int BM = 64, BN = 128;
  __shared__ float sAT[BK][BM + 4];
  __shared__ float sB[BK][BN];
  int tid = threadIdx.x;
  int r0 = blockIdx.y * BM;
  int kc = blockIdx.z;
  int tx = tid & 15, ty = tid >> 4;
  int m0 = ty * 4, n0 = tx * 4;
  float acc0[4][4] = {};
  float acc1[4][4] = {};
  for (int k0 = kc * KCH; k0 < (kc + 1) * KCH; k0 += BK) {
    const int AF4 = BM * BK / 4;
    for (int idx = tid; idx < AF4; idx += 256) {
      int r = idx / (BK / 4);
      int kq = idx % (BK / 4);
      int row = r0 + r;
      float4 v = make_float4(0.f, 0.f, 0.f, 0.f);
      if (row < NN) v = *reinterpret_cast<const float4*>(&z[(size_t)row * KTOT + k0 + kq * 4]);
      sAT[kq * 4 + 0][r] = v.x;
      sAT[kq * 4 + 1][r] = v.y;
      sAT[kq * 4 + 2][r] = v.z;
      sAT[kq * 4 + 3][r] = v.w;
    }
    const int BF4 = BK * BN / 4;          // 1024
    for (int idx = tid; idx < BF4; idx += 256) {
      int kr = idx >> 5, nq = idx & 31;
      int kk = k0 + kr;
      int h = kk / KH, k = kk % KH;
      float4 v = *reinterpret_cast<const float4*>(&W[(size_t)k * OUTC + h * HID + nq * 4]);
      *reinterpret_cast<float4*>(&sB[kr][nq * 4]) = v;
    }
    __syncthreads();
#pragma unroll 4
    for (int kk = 0; kk < BK; ++kk) {
      float4 a = *reinterpret_cast<const float4*>(&sAT[kk][m0]);
      float4 b0 = *reinterpret_cast<const float4*>(&sB[kk][n0]);
      float4 b1 = *reinterpret_cast<const float4*>(&sB[kk][64 + n0]);
      acc0[0][0] += a.x * b0.x; acc0[0][1] += a.x * b0.y; acc0[0][2] += a.x * b0.z; acc0[0][3] += a.x * b0.w;
      acc0[1][0] += a.y * b0.x; acc0[1][1] += a.y * b0.y; acc0[1][2] += a.y * b0.z; acc0[1][3] += a.y * b0.w;
      acc0[2][0] += a.z * b0.x; acc0[2][1] += a.z * b0.y; acc0[2][2] += a.z * b0.z; acc0[2][3] += a.z * b0.w;
      acc0[3][0] += a.w * b0.x; acc0[3][1] += a.w * b0.y; acc0[3][2] += a.w * b0.z; acc0[3][3] += a.w * b0.w;
      acc1[0][0] += a.x * b1.x; acc1[0][1] += a.x * b1.y; acc1[0][2] += a.x * b1.z; acc1[0][3] += a.x * b1.w;
      acc1[1][0] += a.y * b1.x; acc1[1][1] += a.y * b1.y; acc1[1][2] += a.y * b1.z; acc1[1][3] += a.y * b1.w;
      acc1[2][0] += a.z * b1.x; acc1[2][1] += a.z * b1.y; acc1[2][2] += a.z * b1.z; acc1[2][3] += a.z * b1.w;
      acc1[3][0] += a.w * b1.x; acc1[3][1] += a.w * b1.y; acc1[3][2] += a.w * b1.z; acc1[3][3] += a.w * b1.w;
    }
    __syncthreads();
  }
#pragma unroll
  for (int i = 0; i < 4; ++i) {
    int row = r0 + m0 + i;
    if (row < NN) {
      float4 v0 = make_float4(acc0[i][0], acc0[i][1], acc0[i][2], acc0[i][3]);
      float4 v1 = make_float4(acc1[i][0], acc1[i][1], acc1[i][2], acc1[i][3]);
      float* pr = &part[((size_t)kc * NN + row) * HID];
      *reinterpret_cast<float4*>(&pr[n0]) = v0;
      *reinterpret_cast<float4*>(&pr[64 + n0]) = v1;
    }
  }
}

// ---------------- epilogue: sum NKC partials + bias + relu (+pool) ----------------
template <int POOL, int NKC>
__global__ void k_epi(const float* __restrict__ part, const float* __restrict__ bias,
                      const int* __restrict__ batch, float* __restrict__ xout,
                      float* __restrict__ gsums) {
  int tid = threadIdx.x;
  int row = blockIdx.x * 2 + (tid >> 7);
  int c = tid & 127;
  float o = bias[c];
#pragma unroll
  for (int kc = 0; kc < NKC; ++kc)
    o += part[((size_t)kc * NN + row) * HID + c];
  o = fmaxf(o, 0.f);
  if (POOL) {
    atomicAdd(&gsums[(size_t)batch[row] * HID + c], o);
  } else {
    xout[(size_t)row * HID + c] = o;
  }
}

// ---------------- epilogue FUSED with next layer's logits ----------------
template <int NKC>
__global__ void k_epi_esd(const float* __restrict__ part, const float* __restrict__ bias,
                          float* __restrict__ xout, const float* __restrict__ watt,
                          float* __restrict__ es, float* __restrict__ ed) {
  __shared__ float sx[2][HID];
  int tid = threadIdx.x;
  int slot = tid >> 7;
  int row = blockIdx.x * 2 + slot;
  int c = tid & 127;
  float o = bias[c];
#pragma unroll
  for (int kc = 0; kc < NKC; ++kc)
    o += part[((size_t)kc * NN + row) * HID + c];
  o = fmaxf(o, 0.f);
  xout[(size_t)row * HID + c] = o;
  sx[slot][c] = o;
  __syncthreads();
  int t = tid & 127;
  if (t < 8) {
    int r = blockIdx.x * 2 + slot;
    float acc = 0.f;
#pragma unroll 16
    for (int k = 0; k < HID; ++k) acc += sx[slot][k] * watt[k * 8 + t];
    if (t < 4) es[r * 4 + t] = acc;
    else       ed[r * 4 + (t - 4)] = acc;
  }
}

// ---------------- MLP head ----------------
__global__ void k_mlp(const float* __restrict__ sums, const int* __restrict__ batch,
                      const float* __restrict__ bst, const float* __restrict__ M1,
                      const float* __restrict__ mb1, const float* __restrict__ M2,
                      const float* __restrict__ mb2, const float* __restrict__ M3,
                      const float* __restrict__ mb3, float* __restrict__ out) {
  int g = blockIdx.x, tid = threadIdx.x;  // 128 threads
  int lo = 0, hi = NN;
  while (lo < hi) { int mid = (lo + hi) >> 1; if (batch[mid] < g) lo = mid + 1; else hi = mid; }
  int s = lo;
  lo = s; hi = NN;
  while (lo < hi) { int mid = (lo + hi) >> 1; if (batch[mid] < g + 1) lo = mid + 1; else hi = mid; }
  int e = lo;
  float cnt = (float)(e - s);
  float pooled = sums[g * HID + tid] / fmaxf(cnt, 1.f);
  __shared__ float z[HID + 1];
  __shared__ float z1[HID];
  __shared__ float z2[64];
  z[tid] = pooled;
  if (tid == 0) z[HID] = log1pf(bst[g]);
  __syncthreads();
  float a1 = mb1[tid];
  for (int k = 0; k < HID + 1; ++k) a1 += z[k] * M1[k * HID + tid];
  z1[tid] = a1 > 0.f ? a1 : 0.f;
  __syncthreads();
  if (tid < 64) {
    float a2 = mb2[tid];
    for (int k = 0; k < HID; ++k) a2 += z1[k] * M2[k * 64 + tid];
    z2[tid] = a2 > 0.f ? a2 : 0.f;
  }
  __syncthreads();
  if (tid < 2) {
    float a3 = mb3[tid];
    for (int k = 0; k < 64; ++k) a3 += z2[k] * M3[k * 2 + tid];
    out[g * 2 + tid] = a3;
  }
}

extern "C" void kernel_launch(void* const* d_in, const int* in_sizes, int n_in,
                              void* d_out, int out_size, void* d_ws, size_t ws_size,
                              hipStream_t stream) {
  const float* x   = (const float*)d_in[0];
  const int*   ei  = (const int*)d_in[1];
  const int*   bat = (const int*)d_in[2];
  const float* bst = (const float*)d_in[3];
  const float* W1 = (const float*)d_in[4];
  const float* as1 = (const float*)d_in[5];
  const float* ad1 = (const float*)d_in[6];
  const float* b1 = (const float*)d_in[7];
  const float* W2 = (const float*)d_in[8];
  const float* as2 = (const float*)d_in[9];
  const float* ad2 = (const float*)d_in[10];
  const float* b2 = (const float*)d_in[11];
  const float* W3 = (const float*)d_in[12];
  const float* as3 = (const float*)d_in[13];
  const float* ad3 = (const float*)d_in[14];
  const float* b3 = (const float*)d_in[15];
  const float* M1 = (const float*)d_in[16];
  const float* mb1 = (const float*)d_in[17];
  const float* M2 = (const float*)d_in[18];
  const float* mb2 = (const float*)d_in[19];
  const float* M3 = (const float*)d_in[20];
  const float* mb3 = (const float*)d_in[21];
  float* out = (float*)d_out;

  // x4 K-split is the measured optimum (r15-r19): x8 doubled partial traffic and
  // regressed; x2 under-fills the grid. part = 4*NN*128*4 = 41MB.
  const bool use4 = ws_size >= (size_t)110 * 1024 * 1024;

  char* ws = (char*)d_ws;
  auto alloc = [&](size_t bytes) -> void* {
    void* p = (void*)ws;
    ws += (bytes + 255) & ~(size_t)255;
    return p;
  };
  float* z_buf  = (float*)alloc((size_t)NN * OUTC * 4);   // aggregated x (41MB)
  float* z1_buf = (float*)alloc((size_t)NN * 48 * 4);
  float* x_buf  = (float*)alloc((size_t)NN * HID * 4);
  float* e_src  = (float*)alloc((size_t)NN * 4 * 4);
  float* e_dst  = (float*)alloc((size_t)NN * 4 * 4);
  int*   deg    = (int*)alloc((size_t)NN * 4);
  int*   rowst  = (int*)alloc((size_t)(NN + 1) * 4);
  int*   cursor = (int*)alloc((size_t)NN * 4);
  int*   csr    = (int*)alloc((size_t)ET * 4);
  float* part   = (float*)alloc((size_t)(use4 ? 4 : 2) * NN * HID * 4);
  float* watt1  = (float*)alloc((size_t)12 * 8 * 4);
  float* watt2  = (float*)alloc((size_t)HID * 8 * 4);
  float* watt3  = (float*)alloc((size_t)HID * 8 * 4);
  float* gsums  = (float*)alloc((size_t)NG * HID * 4);

  // CSR by destination
  hipMemsetAsync(deg, 0, (size_t)NN * 4, stream);
  hipMemsetAsync(gsums, 0, (size_t)NG * HID * 4, stream);
  k_hist<<<(ET + 255) / 256, 256, 0, stream>>>(ei, deg);
  k_scan<<<1, 1024, 0, stream>>>(deg, rowst, cursor);
  k_scatter<<<(ET + 255) / 256, 256, 0, stream>>>(ei, cursor, csr);
  k_watt3<<<268, 256, 0, stream>>>(W1, as1, ad1, W2, as2, ad2, W3, as3, ad3,
                                   watt1, watt2, watt3);

  dim3 pgrid(NN / 4);
  dim3 g1grid(2, (NN + 63) / 64);
  dim3 ks4grid(1, (NN + 63) / 64, 4);
  dim3 ks2grid(1, (NN + 63) / 64, 2);
  dim3 epigrid(NN / 2);
  // ---- layer 1 (K=12) ----
  k_esd1<<<(NN + 255) / 256, 256, 0, stream>>>(x, watt1, e_src, e_dst);
  k_aggf1<<<pgrid, 256, 0, stream>>>(x, e_src, e_dst, rowst, csr, z1_buf);
  k_gemm_full<48, 12, 48><<<g1grid, 256, 0, stream>>>(z1_buf, W1, b1, x_buf);
  // ---- layer 2 (K=128) ----
  k_esd128<<<NN / 32, 256, 0, stream>>>(x_buf, watt2, e_src, e_dst);
  k_aggf<<<pgrid, 256, 0, stream>>>(x_buf, e_src, e_dst, rowst, csr, z_buf);
  if (use4) {
    k_gemm_ks<512, 128, 32, 128><<<ks4grid, 256, 0, stream>>>(z_buf, W2, part);
    k_epi_esd<4><<<epigrid, 256, 0, stream>>>(part, b2, x_buf, watt3, e_src, e_dst);
  } else {
    k_gemm_ks<512, 128, 32, 256><<<ks2grid, 256, 0, stream>>>(z_buf, W2, part);
    k_epi_esd<2><<<epigrid, 256, 0, stream>>>(part, b2, x_buf, watt3, e_src, e_dst);
  }
  // ---- layer 3 (K=128, fused pool; es/ed already computed by k_epi_esd) ----
  k_aggf<<<pgrid, 256, 0, stream>>>(x_buf, e_src, e_dst, rowst, csr, z_buf);
  if (use4) {
    k_gemm_ks<512, 128, 32, 128><<<ks4grid, 256, 0, stream>>>(z_buf, W3, part);
    k_epi<1, 4><<<epigrid, 256, 0, stream>>>(part, b3, bat, x_buf, gsums);
  } else {
    k_gemm_ks<512, 128, 32, 256><<<ks2grid, 256, 0, stream>>>(z_buf, W3, part);
    k_epi<1, 2><<<epigrid, 256, 0, stream>>>(part, b3, bat, x_buf, gsums);
  }
  // ---- MLP head ----
  k_mlp<<<NG, 128, 0, stream>>>(gsums, bat, bst, M1, mb1, M2, mb2, M3, mb3, out);
}

// Round 21
// 320.534 us; speedup vs baseline: 1.0318x; 1.0275x over previous
//
#include <hip/hip_runtime.h>
#include <hip/hip_bf16.h>
#include <math.h>

#define NN 20000          // nodes
#define NE 320000         // edges (without self loops)
#define ET (NE + NN)      // edges + self loops
#define NG 64             // graphs
#define HEADS 4
#define HID 128
#define OUTC (HEADS * HID)   // 512
#define SLOPE 0.2f

__device__ __forceinline__ float lrelu(float v) { return v > 0.f ? v : SLOPE * v; }

// ---------------- CSR build ----------------
__global__ void k_hist(const int* __restrict__ ei, int* __restrict__ deg) {
  int e = blockIdx.x * blockDim.x + threadIdx.x;
  if (e >= ET) return;
  int dst = (e < NE) ? ei[NE + e] : (e - NE);
  atomicAdd(&deg[dst], 1);
}

__global__ void k_scan(const int* __restrict__ deg, int* __restrict__ row_start,
                       int* __restrict__ cursor) {
  __shared__ int sums[1024];
  int tid = threadIdx.x;
  const int PER = (NN + 1023) / 1024;   // 20
  int base = tid * PER;
  int local = 0;
  for (int i = 0; i < PER; ++i) { int idx = base + i; if (idx < NN) local += deg[idx]; }
  sums[tid] = local;
  __syncthreads();
  for (int off = 1; off < 1024; off <<= 1) {
    int v = (tid >= off) ? sums[tid - off] : 0;
    __syncthreads();
    sums[tid] += v;
    __syncthreads();
  }
  int run = sums[tid] - local;  // exclusive prefix
  for (int i = 0; i < PER; ++i) {
    int idx = base + i;
    if (idx < NN) { row_start[idx] = run; cursor[idx] = run; run += deg[idx]; }
  }
  if (tid == 1023) row_start[NN] = sums[1023];
}

__global__ void k_scatter(const int* __restrict__ ei, int* __restrict__ cursor,
                          int* __restrict__ csr_src) {
  int e = blockIdx.x * blockDim.x + threadIdx.x;
  if (e >= ET) return;
  int src, dst;
  if (e < NE) { src = ei[e]; dst = ei[NE + e]; }
  else        { src = e - NE; dst = src; }
  int pos = atomicAdd(&cursor[dst], 1);
  csr_src[pos] = src;
}

// ---------------- merged watt for all 3 layers ----------------
__global__ void k_watt3(const float* __restrict__ W1, const float* __restrict__ as1,
                        const float* __restrict__ ad1, const float* __restrict__ W2,
                        const float* __restrict__ as2, const float* __restrict__ ad2,
                        const float* __restrict__ W3, const float* __restrict__ as3,
                        const float* __restrict__ ad3, float* __restrict__ watt1,
                        float* __restrict__ watt2, float* __restrict__ watt3) {
  int b = blockIdx.x;   // 0..267
  const float *W, *as, *ad;
  float* wo;
  int k;
  if (b < 12)       { k = b;       W = W1; as = as1; ad = ad1; wo = watt1; }
  else if (b < 140) { k = b - 12;  W = W2; as = as2; ad = ad2; wo = watt2; }
  else              { k = b - 140; W = W3; as = as3; ad = ad3; wo = watt3; }
  int tid = threadIdx.x;          // 256 = 32 c-chunks x 8 t
  int t = tid & 7, h = t & 3;
  int c0 = (tid >> 3) * 4;
  const float* av = (t < 4 ? as : ad) + h * HID;
  const float* wr = W + (size_t)k * OUTC + h * HID;
  float4 wv = *reinterpret_cast<const float4*>(&wr[c0]);
  float4 a4 = *reinterpret_cast<const float4*>(&av[c0]);
  float p = wv.x * a4.x + wv.y * a4.y + wv.z * a4.z + wv.w * a4.w;
  __shared__ float lp[32][8];
  lp[tid >> 3][t] = p;
  __syncthreads();
  if (tid < 8) {
    float s = 0.f;
    for (int cc = 0; cc < 32; ++cc) s += lp[cc][tid];
    wo[k * 8 + tid] = s;
  }
}

// ---------------- attention logits, K=12 (layer 1): thread per node ----------------
__global__ void k_esd1(const float* __restrict__ x, const float* __restrict__ watt,
                       float* __restrict__ es, float* __restrict__ ed) {
  int n = blockIdx.x * blockDim.x + threadIdx.x;
  if (n >= NN) return;
  float xr[12];
#pragma unroll
  for (int k = 0; k < 12; ++k) xr[k] = x[(size_t)n * 12 + k];
#pragma unroll
  for (int t = 0; t < 8; ++t) {
    float acc = 0.f;
#pragma unroll
    for (int k = 0; k < 12; ++k) acc += xr[k] * watt[k * 8 + t];
    if (t < 4) es[n * 4 + t] = acc;
    else       ed[n * 4 + (t - 4)] = acc;
  }
}

// ---------------- attention logits, K=128: THREAD per (node, t) ----------------
__global__ void __launch_bounds__(256) k_esd128(
    const float* __restrict__ x, const float* __restrict__ watt,
    float* __restrict__ es, float* __restrict__ ed) {
  __shared__ float sw[HID * 8];
  int tid = threadIdx.x;
  for (int i = tid; i < HID * 8; i += 256) sw[i] = watt[i];
  __syncthreads();
  int local = tid >> 3;        // 0..31
  int t = tid & 7;
  int n = blockIdx.x * 32 + local;   // NN % 32 == 0
  const float4* xr = reinterpret_cast<const float4*>(&x[(size_t)n * HID]);
  float acc = 0.f;
#pragma unroll 8
  for (int kq = 0; kq < 32; ++kq) {
    float4 xv = xr[kq];
    acc += xv.x * sw[(kq * 4 + 0) * 8 + t] + xv.y * sw[(kq * 4 + 1) * 8 + t]
         + xv.z * sw[(kq * 4 + 2) * 8 + t] + xv.w * sw[(kq * 4 + 3) * 8 + t];
  }
  if (t < 4) es[n * 4 + t] = acc;
  else       ed[n * 4 + (t - 4)] = acc;
}

// ---------------- FUSED softmax + x-aggregation, K=128 (layers 2/3) ----------------
__global__ void __launch_bounds__(256, 4) k_aggf(
    const float* __restrict__ x, const float* __restrict__ es,
    const float* __restrict__ ed, const int* __restrict__ row_start,
    const int* __restrict__ csr_src, float* __restrict__ z) {
  __shared__ float sal[4][256];
  int wid = threadIdx.x >> 6;
  int lane = threadIdx.x & 63;
  int n = blockIdx.x * 4 + wid;          // NN % 4 == 0
  int start = row_start[n];
  int deg = row_start[n + 1] - start;
  const int* sp = csr_src + start;
  float4 edv = *reinterpret_cast<const float4*>(&ed[(size_t)n * 4]);
  int c = lane * 2;
  float2 a0c = make_float2(0.f, 0.f), a1c = make_float2(0.f, 0.f);
  float2 a2c = make_float2(0.f, 0.f), a3c = make_float2(0.f, 0.f);
  float d0 = 0.f, d1 = 0.f, d2 = 0.f, d3 = 0.f;
  for (int cb = 0; cb < deg; cb += 64) {
    int m = min(64, deg - cb);
    {
      int kk = cb + ((lane < m) ? lane : (m - 1));   // clamp (m >= 1 always)
      int s = sp[kk];
      float4 e4 = *reinterpret_cast<const float4*>(&es[(size_t)s * 4]);
      float4 ex;
      ex.x = __expf(lrelu(e4.x + edv.x));
      ex.y = __expf(lrelu(e4.y + edv.y));
      ex.z = __expf(lrelu(e4.z + edv.z));
      ex.w = __expf(lrelu(e4.w + edv.w));
      if (lane < m) {
        *reinterpret_cast<float4*>(&sal[wid][lane * 4]) = ex;
        d0 += ex.x; d1 += ex.y; d2 += ex.z; d3 += ex.w;
      }
    }
    asm volatile("s_waitcnt lgkmcnt(0)" ::: "memory");  // cross-lane LDS RAW fence
    int j = 0;
    for (; j + 4 <= m; j += 4) {
      float4 q0 = *reinterpret_cast<const float4*>(&sal[wid][(j + 0) * 4]);
      float4 q1 = *reinterpret_cast<const float4*>(&sal[wid][(j + 1) * 4]);
      float4 q2 = *reinterpret_cast<const float4*>(&sal[wid][(j + 2) * 4]);
      float4 q3 = *reinterpret_cast<const float4*>(&sal[wid][(j + 3) * 4]);
      int s0 = sp[cb + j + 0], s1 = sp[cb + j + 1];
      int s2 = sp[cb + j + 2], s3 = sp[cb + j + 3];
      float2 x0 = *reinterpret_cast<const float2*>(&x[(size_t)s0 * HID + c]);
      float2 x1 = *reinterpret_cast<const float2*>(&x[(size_t)s1 * HID + c]);
      float2 x2 = *reinterpret_cast<const float2*>(&x[(size_t)s2 * HID + c]);
      float2 x3 = *reinterpret_cast<const float2*>(&x[(size_t)s3 * HID + c]);
      a0c.x += q0.x * x0.x; a0c.y += q0.x * x0.y;
      a1c.x += q0.y * x0.x; a1c.y += q0.y * x0.y;
      a2c.x += q0.z * x0.x; a2c.y += q0.z * x0.y;
      a3c.x += q0.w * x0.x; a3c.y += q0.w * x0.y;
      a0c.x += q1.x * x1.x; a0c.y += q1.x * x1.y;
      a1c.x += q1.y * x1.x; a1c.y += q1.y * x1.y;
      a2c.x += q1.z * x1.x; a2c.y += q1.z * x1.y;
      a3c.x += q1.w * x1.x; a3c.y += q1.w * x1.y;
      a0c.x += q2.x * x2.x; a0c.y += q2.x * x2.y;
      a1c.x += q2.y * x2.x; a1c.y += q2.y * x2.y;
      a2c.x += q2.z * x2.x; a2c.y += q2.z * x2.y;
      a3c.x += q2.w * x2.x; a3c.y += q2.w * x2.y;
      a0c.x += q3.x * x3.x; a0c.y += q3.x * x3.y;
      a1c.x += q3.y * x3.x; a1c.y += q3.y * x3.y;
      a2c.x += q3.z * x3.x; a2c.y += q3.z * x3.y;
      a3c.x += q3.w * x3.x; a3c.y += q3.w * x3.y;
    }
    for (; j < m; ++j) {
      float4 q = *reinterpret_cast<const float4*>(&sal[wid][j * 4]);
      int s = sp[cb + j];
      float2 xv = *reinterpret_cast<const float2*>(&x[(size_t)s * HID + c]);
      a0c.x += q.x * xv.x; a0c.y += q.x * xv.y;
      a1c.x += q.y * xv.x; a1c.y += q.y * xv.y;
      a2c.x += q.z * xv.x; a2c.y += q.z * xv.y;
      a3c.x += q.w * xv.x; a3c.y += q.w * xv.y;
    }
  }
#pragma unroll
  for (int off = 1; off < 64; off <<= 1) {
    d0 += __shfl_xor(d0, off);
    d1 += __shfl_xor(d1, off);
    d2 += __shfl_xor(d2, off);
    d3 += __shfl_xor(d3, off);
  }
  float i0 = 0.25f / d0, i1 = 0.25f / d1, i2 = 0.25f / d2, i3 = 0.25f / d3;
  a0c.x *= i0; a0c.y *= i0;
  a1c.x *= i1; a1c.y *= i1;
  a2c.x *= i2; a2c.y *= i2;
  a3c.x *= i3; a3c.y *= i3;
  float* zr = z + (size_t)n * OUTC;
  *reinterpret_cast<float2*>(&zr[0 * HID + c]) = a0c;
  *reinterpret_cast<float2*>(&zr[1 * HID + c]) = a1c;
  *reinterpret_cast<float2*>(&zr[2 * HID + c]) = a2c;
  *reinterpret_cast<float2*>(&zr[3 * HID + c]) = a3c;
}

// ---------------- FUSED softmax + x-aggregation, K=12 (layer 1) ----------------
__global__ void __launch_bounds__(256, 4) k_aggf1(
    const float* __restrict__ x, const float* __restrict__ es,
    const float* __restrict__ ed, const int* __restrict__ row_start,
    const int* __restrict__ csr_src, float* __restrict__ z1) {
  __shared__ float sal[4][256];
  int wid = threadIdx.x >> 6;
  int lane = threadIdx.x & 63;
  int n = blockIdx.x * 4 + wid;
  int start = row_start[n];
  int deg = row_start[n + 1] - start;
  const int* sp = csr_src + start;
  float4 edv = *reinterpret_cast<const float4*>(&ed[(size_t)n * 4]);
  int h = lane >> 4;
  int cr = lane & 15;
  int cc = cr < 12 ? cr : 11;    // clamp: lanes 12-15 compute garbage, never stored
  float acc = 0.f;
  float d0 = 0.f, d1 = 0.f, d2 = 0.f, d3 = 0.f;
  for (int cb = 0; cb < deg; cb += 64) {
    int m = min(64, deg - cb);
    {
      int kk = cb + ((lane < m) ? lane : (m - 1));
      int s = sp[kk];
      float4 e4 = *reinterpret_cast<const float4*>(&es[(size_t)s * 4]);
      float4 ex;
      ex.x = __expf(lrelu(e4.x + edv.x));
      ex.y = __expf(lrelu(e4.y + edv.y));
      ex.z = __expf(lrelu(e4.z + edv.z));
      ex.w = __expf(lrelu(e4.w + edv.w));
      if (lane < m) {
        *reinterpret_cast<float4*>(&sal[wid][lane * 4]) = ex;
        d0 += ex.x; d1 += ex.y; d2 += ex.z; d3 += ex.w;
      }
    }
    asm volatile("s_waitcnt lgkmcnt(0)" ::: "memory");
    int j = 0;
    for (; j + 4 <= m; j += 4) {
      float ah0 = sal[wid][(j + 0) * 4 + h];
      float ah1 = sal[wid][(j + 1) * 4 + h];
      float ah2 = sal[wid][(j + 2) * 4 + h];
      float ah3 = sal[wid][(j + 3) * 4 + h];
      int s0 = sp[cb + j + 0], s1 = sp[cb + j + 1];
      int s2 = sp[cb + j + 2], s3 = sp[cb + j + 3];
      float x0 = x[(size_t)s0 * 12 + cc];
      float x1 = x[(size_t)s1 * 12 + cc];
      float x2 = x[(size_t)s2 * 12 + cc];
      float x3 = x[(size_t)s3 * 12 + cc];
      acc += ah0 * x0 + ah1 * x1 + ah2 * x2 + ah3 * x3;
    }
    for (; j < m; ++j) {
      float ah = sal[wid][j * 4 + h];
      int s = sp[cb + j];
      acc += ah * x[(size_t)s * 12 + cc];
    }
  }
#pragma unroll
  for (int off = 1; off < 64; off <<= 1) {
    d0 += __shfl_xor(d0, off);
    d1 += __shfl_xor(d1, off);
    d2 += __shfl_xor(d2, off);
    d3 += __shfl_xor(d3, off);
  }
  float dh = (h == 0) ? d0 : (h == 1) ? d1 : (h == 2) ? d2 : d3;
  float ivh = 0.25f / dh;
  if (cr < 12) z1[(size_t)n * 48 + h * 12 + cr] = acc * ivh;
}

// ---------------- full-K GEMM with fused epilogue (layer 1, K=48) ----------------
template <int KTOT, int KH, int BK>
__global__ void k_gemm_full(const float* __restrict__ z, const float* __restrict__ W,
                            const float* __restrict__ bias, float* __restrict__ xout) {
  const int BM = 64, BN = 64;
  __shared__ float sAT[BK][BM + 4];
  __shared__ float sB[BK][BN];
  int tid = threadIdx.x;
  int r0 = blockIdx.y * BM;
  int cb = blockIdx.x * BN;
  int tx = tid & 15, ty = tid >> 4;
  int m0 = ty * 4, n0 = tx * 4;
  float acc[4][4] = {};
  for (int k0 = 0; k0 < KTOT; k0 += BK) {
    const int AF4 = BM * BK / 4;
    for (int idx = tid; idx < AF4; idx += 256) {
      int r = idx / (BK / 4);
      int kq = idx % (BK / 4);
      int row = r0 + r;
      float4 v = make_float4(0.f, 0.f, 0.f, 0.f);
      if (row < NN) v = *reinterpret_cast<const float4*>(&z[(size_t)row * KTOT + k0 + kq * 4]);
      sAT[kq * 4 + 0][r] = v.x;
      sAT[kq * 4 + 1][r] = v.y;
      sAT[kq * 4 + 2][r] = v.z;
      sAT[kq * 4 + 3][r] = v.w;
    }
    const int BF4 = BK * BN / 4;
    for (int idx = tid; idx < BF4; idx += 256) {
      int kr = idx / 16, nq = idx & 15;
      int kk = k0 + kr;
      int h = kk / KH, k = kk % KH;
      float4 v = *reinterpret_cast<const float4*>(&W[(size_t)k * OUTC + h * HID + cb + nq * 4]);
      *reinterpret_cast<float4*>(&sB[kr][nq * 4]) = v;
    }
    __syncthreads();
#pragma unroll 4
    for (int kk = 0; kk < BK; ++kk) {
      float4 a = *reinterpret_cast<const float4*>(&sAT[kk][m0]);
      float4 b = *reinterpret_cast<const float4*>(&sB[kk][n0]);
      acc[0][0] += a.x * b.x; acc[0][1] += a.x * b.y; acc[0][2] += a.x * b.z; acc[0][3] += a.x * b.w;
      acc[1][0] += a.y * b.x; acc[1][1] += a.y * b.y; acc[1][2] += a.y * b.z; acc[1][3] += a.y * b.w;
      acc[2][0] += a.z * b.x; acc[2][1] += a.z * b.y; acc[2][2] += a.z * b.z; acc[2][3] += a.z * b.w;
      acc[3][0] += a.w * b.x; acc[3][1] += a.w * b.y; acc[3][2] += a.w * b.z; acc[3][3] += a.w * b.w;
    }
    __syncthreads();
  }
  float4 bv = *reinterpret_cast<const float4*>(&bias[cb + n0]);
#pragma unroll
  for (int i = 0; i < 4; ++i) {
    int row = r0 + m0 + i;
    if (row < NN) {
      float4 o;
      o.x = fmaxf(acc[i][0] + bv.x, 0.f);
      o.y = fmaxf(acc[i][1] + bv.y, 0.f);
      o.z = fmaxf(acc[i][2] + bv.z, 0.f);
      o.w = fmaxf(acc[i][3] + bv.w, 0.f);
      *reinterpret_cast<float4*>(&xout[(size_t)row * HID + cb + n0]) = o;
    }
  }
}

// ---------------- K-split GEMM: BM=64 x BN=128, NKC chunks ----------------
template <int KTOT, int KH, int BK, int KCH>
__global__ void k_gemm_ks(const float* __restrict__ z, const float* __restrict__ W,
                          float* __restrict__ part) {
  const int BM = 64, BN = 128;
  __shared__ float sAT[BK][BM + 4];
  __shared__ float sB[BK][BN];
  int tid = threadIdx.x;
  int r0 = blockIdx.y * BM;
  int kc = blockIdx.z;
  int tx = tid & 15, ty = tid >> 4;
  int m0 = ty * 4, n0 = tx * 4;
  float acc0[4][4] = {};
  float acc1[4][4] = {};
  for (int k0 = kc * KCH; k0 < (kc + 1) * KCH; k0 += BK) {
    const int AF4 = BM * BK / 4;
    for (int idx = tid; idx < AF4; idx += 256) {
      int r = idx / (BK / 4);
      int kq = idx % (BK / 4);
      int row = r0 + r;
      float4 v = make_float4(0.f, 0.f, 0.f, 0.f);
      if (row < NN) v = *reinterpret_cast<const float4*>(&z[(size_t)row * KTOT + k0 + kq * 4]);
      sAT[kq * 4 + 0][r] = v.x;
      sAT[kq * 4 + 1][r] = v.y;
      sAT[kq * 4 + 2][r] = v.z;
      sAT[kq * 4 + 3][r] = v.w;
    }
    const int BF4 = BK * BN / 4;          // 1024
    for (int idx = tid; idx < BF4; idx += 256) {
      int kr = idx >> 5, nq = idx & 31;
      int kk = k0 + kr;
      int h = kk / KH, k = kk % KH;
      float4 v = *reinterpret_cast<const float4*>(&W[(size_t)k * OUTC + h * HID + nq * 4]);
      *reinterpret_cast<float4*>(&sB[kr][nq * 4]) = v;
    }
    __syncthreads();
#pragma unroll 4
    for (int kk = 0; kk < BK; ++kk) {
      float4 a = *reinterpret_cast<const float4*>(&sAT[kk][m0]);
      float4 b0 = *reinterpret_cast<const float4*>(&sB[kk][n0]);
      float4 b1 = *reinterpret_cast<const float4*>(&sB[kk][64 + n0]);
      acc0[0][0] += a.x * b0.x; acc0[0][1] += a.x * b0.y; acc0[0][2] += a.x * b0.z; acc0[0][3] += a.x * b0.w;
      acc0[1][0] += a.y * b0.x; acc0[1][1] += a.y * b0.y; acc0[1][2] += a.y * b0.z; acc0[1][3] += a.y * b0.w;
      acc0[2][0] += a.z * b0.x; acc0[2][1] += a.z * b0.y; acc0[2][2] += a.z * b0.z; acc0[2][3] += a.z * b0.w;
      acc0[3][0] += a.w * b0.x; acc0[3][1] += a.w * b0.y; acc0[3][2] += a.w * b0.z; acc0[3][3] += a.w * b0.w;
      acc1[0][0] += a.x * b1.x; acc1[0][1] += a.x * b1.y; acc1[0][2] += a.x * b1.z; acc1[0][3] += a.x * b1.w;
      acc1[1][0] += a.y * b1.x; acc1[1][1] += a.y * b1.y; acc1[1][2] += a.y * b1.z; acc1[1][3] += a.y * b1.w;
      acc1[2][0] += a.z * b1.x; acc1[2][1] += a.z * b1.y; acc1[2][2] += a.z * b1.z; acc1[2][3] += a.z * b1.w;
      acc1[3][0] += a.w * b1.x; acc1[3][1] += a.w * b1.y; acc1[3][2] += a.w * b1.z; acc1[3][3] += a.w * b1.w;
    }
    __syncthreads();
  }
#pragma unroll
  for (int i = 0; i < 4; ++i) {
    int row = r0 + m0 + i;
    if (row < NN) {
      float4 v0 = make_float4(acc0[i][0], acc0[i][1], acc0[i][2], acc0[i][3]);
      float4 v1 = make_float4(acc1[i][0], acc1[i][1], acc1[i][2], acc1[i][3]);
      float* pr = &part[((size_t)kc * NN + row) * HID];
      *reinterpret_cast<float4*>(&pr[n0]) = v0;
      *reinterpret_cast<float4*>(&pr[64 + n0]) = v1;
    }
  }
}

// ---------------- epilogue: sum NKC partials + bias + relu (+pool) ----------------
template <int POOL, int NKC>
__global__ void k_epi(const float* __restrict__ part, const float* __restrict__ bias,
                      const int* __restrict__ batch, float* __restrict__ xout,
                      float* __restrict__ gsums) {
  int tid = threadIdx.x;
  int row = blockIdx.x * 2 + (tid >> 7);
  int c = tid & 127;
  float o = bias[c];
#pragma unroll
  for (int kc = 0; kc < NKC; ++kc)
    o += part[((size_t)kc * NN + row) * HID + c];
  o = fmaxf(o, 0.f);
  if (POOL) {
    atomicAdd(&gsums[(size_t)batch[row] * HID + c], o);
  } else {
    xout[(size_t)row * HID + c] = o;
  }
}

// ---------------- MLP head ----------------
__global__ void k_mlp(const float* __restrict__ sums, const int* __restrict__ batch,
                      const float* __restrict__ bst, const float* __restrict__ M1,
                      const float* __restrict__ mb1, const float* __restrict__ M2,
                      const float* __restrict__ mb2, const float* __restrict__ M3,
                      const float* __restrict__ mb3, float* __restrict__ out) {
  int g = blockIdx.x, tid = threadIdx.x;  // 128 threads
  int lo = 0, hi = NN;
  while (lo < hi) { int mid = (lo + hi) >> 1; if (batch[mid] < g) lo = mid + 1; else hi = mid; }
  int s = lo;
  lo = s; hi = NN;
  while (lo < hi) { int mid = (lo + hi) >> 1; if (batch[mid] < g + 1) lo = mid + 1; else hi = mid; }
  int e = lo;
  float cnt = (float)(e - s);
  float pooled = sums[g * HID + tid] / fmaxf(cnt, 1.f);
  __shared__ float z[HID + 1];
  __shared__ float z1[HID];
  __shared__ float z2[64];
  z[tid] = pooled;
  if (tid == 0) z[HID] = log1pf(bst[g]);
  __syncthreads();
  float a1 = mb1[tid];
  for (int k = 0; k < HID + 1; ++k) a1 += z[k] * M1[k * HID + tid];
  z1[tid] = a1 > 0.f ? a1 : 0.f;
  __syncthreads();
  if (tid < 64) {
    float a2 = mb2[tid];
    for (int k = 0; k < HID; ++k) a2 += z1[k] * M2[k * 64 + tid];
    z2[tid] = a2 > 0.f ? a2 : 0.f;
  }
  __syncthreads();
  if (tid < 2) {
    float a3 = mb3[tid];
    for (int k = 0; k < 64; ++k) a3 += z2[k] * M3[k * 2 + tid];
    out[g * 2 + tid] = a3;
  }
}

extern "C" void kernel_launch(void* const* d_in, const int* in_sizes, int n_in,
                              void* d_out, int out_size, void* d_ws, size_t ws_size,
                              hipStream_t stream) {
  const float* x   = (const float*)d_in[0];
  const int*   ei  = (const int*)d_in[1];
  const int*   bat = (const int*)d_in[2];
  const float* bst = (const float*)d_in[3];
  const float* W1 = (const float*)d_in[4];
  const float* as1 = (const float*)d_in[5];
  const float* ad1 = (const float*)d_in[6];
  const float* b1 = (const float*)d_in[7];
  const float* W2 = (const float*)d_in[8];
  const float* as2 = (const float*)d_in[9];
  const float* ad2 = (const float*)d_in[10];
  const float* b2 = (const float*)d_in[11];
  const float* W3 = (const float*)d_in[12];
  const float* as3 = (const float*)d_in[13];
  const float* ad3 = (const float*)d_in[14];
  const float* b3 = (const float*)d_in[15];
  const float* M1 = (const float*)d_in[16];
  const float* mb1 = (const float*)d_in[17];
  const float* M2 = (const float*)d_in[18];
  const float* mb2 = (const float*)d_in[19];
  const float* M3 = (const float*)d_in[20];
  const float* mb3 = (const float*)d_in[21];
  float* out = (float*)d_out;

  // x4 K-split is the measured optimum (r14-r20): x8 doubled partial traffic and
  // regressed; x2 under-fills the grid. part = 4*NN*128*4 = 41MB.
  const bool use4 = ws_size >= (size_t)110 * 1024 * 1024;

  char* ws = (char*)d_ws;
  auto alloc = [&](size_t bytes) -> void* {
    void* p = (void*)ws;
    ws += (bytes + 255) & ~(size_t)255;
    return p;
  };
  float* z_buf  = (float*)alloc((size_t)NN * OUTC * 4);   // aggregated x (41MB)
  float* z1_buf = (float*)alloc((size_t)NN * 48 * 4);
  float* x_buf  = (float*)alloc((size_t)NN * HID * 4);
  float* e_src  = (float*)alloc((size_t)NN * 4 * 4);
  float* e_dst  = (float*)alloc((size_t)NN * 4 * 4);
  int*   deg    = (int*)alloc((size_t)NN * 4);
  int*   rowst  = (int*)alloc((size_t)(NN + 1) * 4);
  int*   cursor = (int*)alloc((size_t)NN * 4);
  int*   csr    = (int*)alloc((size_t)ET * 4);
  float* part   = (float*)alloc((size_t)(use4 ? 4 : 2) * NN * HID * 4);
  float* watt1  = (float*)alloc((size_t)12 * 8 * 4);
  float* watt2  = (float*)alloc((size_t)HID * 8 * 4);
  float* watt3  = (float*)alloc((size_t)HID * 8 * 4);
  float* gsums  = (float*)alloc((size_t)NG * HID * 4);

  // CSR by destination
  hipMemsetAsync(deg, 0, (size_t)NN * 4, stream);
  hipMemsetAsync(gsums, 0, (size_t)NG * HID * 4, stream);
  k_hist<<<(ET + 255) / 256, 256, 0, stream>>>(ei, deg);
  k_scan<<<1, 1024, 0, stream>>>(deg, rowst, cursor);
  k_scatter<<<(ET + 255) / 256, 256, 0, stream>>>(ei, cursor, csr);
  k_watt3<<<268, 256, 0, stream>>>(W1, as1, ad1, W2, as2, ad2, W3, as3, ad3,
                                   watt1, watt2, watt3);

  dim3 pgrid(NN / 4);
  dim3 g1grid(2, (NN + 63) / 64);
  dim3 ks4grid(1, (NN + 63) / 64, 4);
  dim3 ks2grid(1, (NN + 63) / 64, 2);
  dim3 epigrid(NN / 2);
  // ---- layer 1 (K=12) ----
  k_esd1<<<(NN + 255) / 256, 256, 0, stream>>>(x, watt1, e_src, e_dst);
  k_aggf1<<<pgrid, 256, 0, stream>>>(x, e_src, e_dst, rowst, csr, z1_buf);
  k_gemm_full<48, 12, 48><<<g1grid, 256, 0, stream>>>(z1_buf, W1, b1, x_buf);
  // ---- layer 2 (K=128) ----
  k_esd128<<<NN / 32, 256, 0, stream>>>(x_buf, watt2, e_src, e_dst);
  k_aggf<<<pgrid, 256, 0, stream>>>(x_buf, e_src, e_dst, rowst, csr, z_buf);
  if (use4) {
    k_gemm_ks<512, 128, 32, 128><<<ks4grid, 256, 0, stream>>>(z_buf, W2, part);
    k_epi<0, 4><<<epigrid, 256, 0, stream>>>(part, b2, bat, x_buf, gsums);
  } else {
    k_gemm_ks<512, 128, 32, 256><<<ks2grid, 256, 0, stream>>>(z_buf, W2, part);
    k_epi<0, 2><<<epigrid, 256, 0, stream>>>(part, b2, bat, x_buf, gsums);
  }
  // ---- layer 3 (K=128, fused pool) ----
  k_esd128<<<NN / 32, 256, 0, stream>>>(x_buf, watt3, e_src, e_dst);
  k_aggf<<<pgrid, 256, 0, stream>>>(x_buf, e_src, e_dst, rowst, csr, z_buf);
  if (use4) {
    k_gemm_ks<512, 128, 32, 128><<<ks4grid, 256, 0, stream>>>(z_buf, W3, part);
    k_epi<1, 4><<<epigrid, 256, 0, stream>>>(part, b3, bat, x_buf, gsums);
  } else {
    k_gemm_ks<512, 128, 32, 256><<<ks2grid, 256, 0, stream>>>(z_buf, W3, part);
    k_epi<1, 2><<<epigrid, 256, 0, stream>>>(part, b3, bat, x_buf, gsums);
  }
  // ---- MLP head ----
  k_mlp<<<NG, 128, 0, stream>>>(gsums, bat, bst, M1, mb1, M2, mb2, M3, mb3, out);
}